// Round 1
// baseline (523.875 us; speedup 1.0000x reference)
//
#include <hip/hip_runtime.h>
#include <math.h>

#define N_ 1024
#define ROWS_PER_DIR 65536   // B*N = 64*1024
#define TOTAL_ROWS   131072  // 2 directions
#define BLOCKS_K1    32768   // 4 rows (waves) per block

// Kernel 1: one wave (64 lanes) per row. Online row max + sum-exp in one pass.
__global__ __launch_bounds__(256) void row_loss_kernel(
    const float* __restrict__ succ_logits,
    const int*   __restrict__ succ_labels,
    const float* __restrict__ pred_logits,
    const int*   __restrict__ pred_labels,
    const int*   __restrict__ line_mask,
    float*       __restrict__ partials)   // [BLOCKS_K1]
{
    __shared__ float wsum[4];
    const int wave = threadIdx.x >> 6;
    const int lane = threadIdx.x & 63;
    const int r    = blockIdx.x * 4 + wave;   // 0 .. TOTAL_ROWS-1
    const int dir  = r >> 16;                 // 0 = successor, 1 = predecessor
    const int rr   = r & (ROWS_PER_DIR - 1);  // b*N + n
    const int n    = rr & (N_ - 1);

    const float* __restrict__ logits = dir ? pred_logits : succ_logits;
    const int*   __restrict__ labels = dir ? pred_labels : succ_labels;
    const float* __restrict__ row    = logits + (size_t)rr * N_;

    // 16 elements per lane: 4 coalesced float4 loads (each k: wave reads 1 KiB contiguous)
    const float4* row4 = (const float4*)row;
    float4 v0 = row4[0 * 64 + lane];
    float4 v1 = row4[1 * 64 + lane];
    float4 v2 = row4[2 * 64 + lane];
    float4 v3 = row4[3 * 64 + lane];

    float m = v0.x;
    m = fmaxf(m, v0.y); m = fmaxf(m, v0.z); m = fmaxf(m, v0.w);
    m = fmaxf(m, v1.x); m = fmaxf(m, v1.y); m = fmaxf(m, v1.z); m = fmaxf(m, v1.w);
    m = fmaxf(m, v2.x); m = fmaxf(m, v2.y); m = fmaxf(m, v2.z); m = fmaxf(m, v2.w);
    m = fmaxf(m, v3.x); m = fmaxf(m, v3.y); m = fmaxf(m, v3.z); m = fmaxf(m, v3.w);

    float s = 0.0f;
    s += __expf(v0.x - m); s += __expf(v0.y - m); s += __expf(v0.z - m); s += __expf(v0.w - m);
    s += __expf(v1.x - m); s += __expf(v1.y - m); s += __expf(v1.z - m); s += __expf(v1.w - m);
    s += __expf(v2.x - m); s += __expf(v2.y - m); s += __expf(v2.z - m); s += __expf(v2.w - m);
    s += __expf(v3.x - m); s += __expf(v3.y - m); s += __expf(v3.z - m); s += __expf(v3.w - m);

    // wave reduction of (max, sumexp) pairs
    #pragma unroll
    for (int off = 32; off > 0; off >>= 1) {
        float mo = __shfl_xor(m, off);
        float so = __shfl_xor(s, off);
        float M  = fmaxf(m, mo);
        s = s * __expf(m - M) + so * __expf(mo - M);
        m = M;
    }

    if (lane == 0) {
        float nll_masked = 0.0f;
        const int label = labels[rr];
        const int valid = line_mask[rr];
        if (valid) {
            if (label == -1) {
                // self-pointing & valid: diag overwritten with row_max+1, target = diag
                // adjusted sumexp (max = m+1): e^{-1}*(s - e^{d-m}) + 1
                float d = row[n];                              // L1/L2-hot
                float s_adj = (s - __expf(d - m)) * 0.36787944117144233f + 1.0f;
                nll_masked = __logf(s_adj);
            } else {
                int lbl = label < 0 ? 0 : (label > N_ - 1 ? N_ - 1 : label);
                nll_masked = m + __logf(s) - row[lbl];         // L1/L2-hot
            }
        }
        wsum[wave] = nll_masked;
    }
    __syncthreads();
    if (threadIdx.x == 0)
        partials[blockIdx.x] = (wsum[0] + wsum[1]) + (wsum[2] + wsum[3]);
}

// Kernel 2: single-block deterministic finalize.
__global__ __launch_bounds__(1024) void finalize_kernel(
    const float* __restrict__ partials,     // [BLOCKS_K1]: first half succ, second half pred
    const int*   __restrict__ line_mask,
    const float* __restrict__ pred_weight,
    float*       __restrict__ out)
{
    const int tid = threadIdx.x;
    float ssum = 0.0f, psum = 0.0f, msum = 0.0f;
    for (int i = tid; i < BLOCKS_K1 / 2; i += 1024) {
        ssum += partials[i];
        psum += partials[i + BLOCKS_K1 / 2];
    }
    for (int i = tid; i < ROWS_PER_DIR; i += 1024)
        msum += (line_mask[i] != 0) ? 1.0f : 0.0f;

    #pragma unroll
    for (int off = 32; off > 0; off >>= 1) {
        ssum += __shfl_xor(ssum, off);
        psum += __shfl_xor(psum, off);
        msum += __shfl_xor(msum, off);
    }

    __shared__ float sh[3][16];
    const int wave = tid >> 6, lane = tid & 63;
    if (lane == 0) { sh[0][wave] = ssum; sh[1][wave] = psum; sh[2][wave] = msum; }
    __syncthreads();
    if (tid == 0) {
        float S = 0.0f, P = 0.0f, M = 0.0f;
        #pragma unroll
        for (int w = 0; w < 16; ++w) { S += sh[0][w]; P += sh[1][w]; M += sh[2][w]; }
        const float denom = fmaxf(M, 1.0f);
        const float sl = S / denom, pl = P / denom;
        const float w  = pred_weight[0];
        out[0] = sl + w * pl;   // total_loss
        out[1] = sl;            // succ_loss
        out[2] = pl;            // pred_loss
        out[3] = M;             // num_valid
    }
}

extern "C" void kernel_launch(void* const* d_in, const int* in_sizes, int n_in,
                              void* d_out, int out_size, void* d_ws, size_t ws_size,
                              hipStream_t stream) {
    const float* succ_logits = (const float*)d_in[0];
    const int*   succ_labels = (const int*)  d_in[1];
    const float* pred_logits = (const float*)d_in[2];
    const int*   pred_labels = (const int*)  d_in[3];
    const int*   line_mask   = (const int*)  d_in[4];
    const float* pred_weight = (const float*)d_in[5];
    float* out      = (float*)d_out;
    float* partials = (float*)d_ws;   // 32768 floats = 128 KiB

    row_loss_kernel<<<BLOCKS_K1, 256, 0, stream>>>(
        succ_logits, succ_labels, pred_logits, pred_labels, line_mask, partials);
    finalize_kernel<<<1, 1024, 0, stream>>>(partials, line_mask, pred_weight, out);
}

// Round 2
// 494.333 us; speedup vs baseline: 1.0598x; 1.0598x over previous
//
#include <hip/hip_runtime.h>
#include <math.h>

#define N_ 1024
#define ROWS_PER_DIR 65536   // B*N = 64*1024
#define TOTAL_ROWS   131072  // 2 directions
#define WAVES_PER_BLOCK 8
#define BLOCKS_K1    (TOTAL_ROWS / WAVES_PER_BLOCK)   // 16384

typedef float v4f __attribute__((ext_vector_type(4)));

// Kernel 1: one wave (64 lanes) per row; 16 fp32/lane held in registers.
// Two-phase reduction (max, then sum-exp at global max). The target element
// (diagonal for self-pointing rows, label element otherwise) is extracted
// from the owning lane's registers and broadcast -- no dependent global
// re-read after the reduction.
__global__ __launch_bounds__(512) void row_loss_kernel(
    const float* __restrict__ succ_logits,
    const int*   __restrict__ succ_labels,
    const float* __restrict__ pred_logits,
    const int*   __restrict__ pred_labels,
    const int*   __restrict__ line_mask,
    float*       __restrict__ partials)   // [BLOCKS_K1]
{
    __shared__ float wsum[WAVES_PER_BLOCK];
    const int wave = threadIdx.x >> 6;
    const int lane = threadIdx.x & 63;
    const int r    = blockIdx.x * WAVES_PER_BLOCK + wave;  // 0 .. TOTAL_ROWS-1
    const int dir  = r >> 16;                 // 0 = successor, 1 = predecessor
    const int rr   = r & (ROWS_PER_DIR - 1);  // b*N + n
    const int n    = rr & (N_ - 1);

    const float* __restrict__ logits = dir ? pred_logits : succ_logits;
    const int*   __restrict__ labels = dir ? pred_labels : succ_labels;
    const float* __restrict__ row    = logits + (size_t)rr * N_;

    // wave-uniform metadata first (single cacheline, broadcast)
    const int label = labels[rr];
    const int valid = line_mask[rr];

    // 16 elements per lane: 4 coalesced nontemporal float4 loads
    const v4f* row4 = (const v4f*)row;
    v4f v0 = __builtin_nontemporal_load(row4 + 0 * 64 + lane);
    v4f v1 = __builtin_nontemporal_load(row4 + 1 * 64 + lane);
    v4f v2 = __builtin_nontemporal_load(row4 + 2 * 64 + lane);
    v4f v3 = __builtin_nontemporal_load(row4 + 3 * 64 + lane);

    // target index: diagonal if self-pointing, else clamped label
    const int t      = (label == -1) ? n : (label < 0 ? 0 : (label > N_ - 1 ? N_ - 1 : label));
    const int t_lane = (t >> 2) & 63;
    const int t_k    = t >> 8;
    const int t_c    = t & 3;
    v4f tv = (t_k == 0) ? v0 : (t_k == 1) ? v1 : (t_k == 2) ? v2 : v3;
    const float x_t = __shfl(tv[t_c], t_lane);   // row[t], wave-uniform after shfl

    // phase 1: row max
    float m;
    {
        v4f a = v0, b = v1;
        a.x = fmaxf(a.x, b.x); a.y = fmaxf(a.y, b.y); a.z = fmaxf(a.z, b.z); a.w = fmaxf(a.w, b.w);
        v4f c = v2; b = v3;
        c.x = fmaxf(c.x, b.x); c.y = fmaxf(c.y, b.y); c.z = fmaxf(c.z, b.z); c.w = fmaxf(c.w, b.w);
        a.x = fmaxf(a.x, c.x); a.y = fmaxf(a.y, c.y); a.z = fmaxf(a.z, c.z); a.w = fmaxf(a.w, c.w);
        m = fmaxf(fmaxf(a.x, a.y), fmaxf(a.z, a.w));
    }
    #pragma unroll
    for (int off = 32; off > 0; off >>= 1)
        m = fmaxf(m, __shfl_xor(m, off));

    // phase 2: sum of exp(x - m) at the global row max
    float s = 0.0f;
    s += __expf(v0.x - m); s += __expf(v0.y - m); s += __expf(v0.z - m); s += __expf(v0.w - m);
    s += __expf(v1.x - m); s += __expf(v1.y - m); s += __expf(v1.z - m); s += __expf(v1.w - m);
    s += __expf(v2.x - m); s += __expf(v2.y - m); s += __expf(v2.z - m); s += __expf(v2.w - m);
    s += __expf(v3.x - m); s += __expf(v3.y - m); s += __expf(v3.z - m); s += __expf(v3.w - m);
    #pragma unroll
    for (int off = 32; off > 0; off >>= 1)
        s += __shfl_xor(s, off);

    if (lane == 0) {
        float nll = 0.0f;
        if (valid) {
            if (label == -1) {
                // diag overwritten with row_max+1, target = diag:
                // nll = log( e^{-1} * (s - e^{d-m}) + 1 ),  d = row[n] = x_t
                nll = __logf((s - __expf(x_t - m)) * 0.36787944117144233f + 1.0f);
            } else {
                nll = m + __logf(s) - x_t;
            }
        }
        wsum[wave] = nll;
    }
    __syncthreads();
    if (threadIdx.x == 0) {
        float acc = 0.0f;
        #pragma unroll
        for (int w = 0; w < WAVES_PER_BLOCK; ++w) acc += wsum[w];
        partials[blockIdx.x] = acc;
    }
}

// Kernel 2: single-block deterministic finalize.
// partials: blocks 0..8191 are successor rows, 8192..16383 predecessor rows.
__global__ __launch_bounds__(1024) void finalize_kernel(
    const float* __restrict__ partials,
    const int*   __restrict__ line_mask,
    const float* __restrict__ pred_weight,
    float*       __restrict__ out)
{
    const int tid = threadIdx.x;
    float ssum = 0.0f, psum = 0.0f, msum = 0.0f;
    for (int i = tid; i < BLOCKS_K1 / 2; i += 1024) {
        ssum += partials[i];
        psum += partials[i + BLOCKS_K1 / 2];
    }
    for (int i = tid; i < ROWS_PER_DIR; i += 1024)
        msum += (line_mask[i] != 0) ? 1.0f : 0.0f;

    #pragma unroll
    for (int off = 32; off > 0; off >>= 1) {
        ssum += __shfl_xor(ssum, off);
        psum += __shfl_xor(psum, off);
        msum += __shfl_xor(msum, off);
    }

    __shared__ float sh[3][16];
    const int wave = tid >> 6, lane = tid & 63;
    if (lane == 0) { sh[0][wave] = ssum; sh[1][wave] = psum; sh[2][wave] = msum; }
    __syncthreads();
    if (tid == 0) {
        float S = 0.0f, P = 0.0f, M = 0.0f;
        #pragma unroll
        for (int w = 0; w < 16; ++w) { S += sh[0][w]; P += sh[1][w]; M += sh[2][w]; }
        const float denom = fmaxf(M, 1.0f);
        const float sl = S / denom, pl = P / denom;
        const float w  = pred_weight[0];
        out[0] = sl + w * pl;   // total_loss
        out[1] = sl;            // succ_loss
        out[2] = pl;            // pred_loss
        out[3] = M;             // num_valid
    }
}

extern "C" void kernel_launch(void* const* d_in, const int* in_sizes, int n_in,
                              void* d_out, int out_size, void* d_ws, size_t ws_size,
                              hipStream_t stream) {
    const float* succ_logits = (const float*)d_in[0];
    const int*   succ_labels = (const int*)  d_in[1];
    const float* pred_logits = (const float*)d_in[2];
    const int*   pred_labels = (const int*)  d_in[3];
    const int*   line_mask   = (const int*)  d_in[4];
    const float* pred_weight = (const float*)d_in[5];
    float* out      = (float*)d_out;
    float* partials = (float*)d_ws;   // 16384 floats = 64 KiB

    row_loss_kernel<<<BLOCKS_K1, 512, 0, stream>>>(
        succ_logits, succ_labels, pred_logits, pred_labels, line_mask, partials);
    finalize_kernel<<<1, 1024, 0, stream>>>(partials, line_mask, pred_weight, out);
}

// Round 3
// 479.900 us; speedup vs baseline: 1.0916x; 1.0301x over previous
//
#include <hip/hip_runtime.h>
#include <math.h>

#define N_ 1024
#define ROWS_PER_DIR 65536   // B*N = 64*1024
#define TOTAL_ROWS   131072  // 2 directions
#define WAVES_PER_BLOCK 8
#define BLOCKS_K1    (TOTAL_ROWS / WAVES_PER_BLOCK)   // 16384
#define BLOCKS_PER_DIR (BLOCKS_K1 / 2)                // 8192

typedef float v4f __attribute__((ext_vector_type(4)));
typedef float v2f __attribute__((ext_vector_type(2)));

// Kernel 1: one wave (64 lanes) per row; 16 fp32/lane held in registers.
// Two-phase reduction (max, then sum-exp at global max). Target element
// (diagonal for self-pointing rows, label element otherwise) extracted from
// the owning lane's registers and broadcast -- no dependent global re-read.
// Each block also counts its valid lines (dir==0 blocks only), so finalize
// never has to touch line_mask.
__global__ __launch_bounds__(512) void row_loss_kernel(
    const float* __restrict__ succ_logits,
    const int*   __restrict__ succ_labels,
    const float* __restrict__ pred_logits,
    const int*   __restrict__ pred_labels,
    const int*   __restrict__ line_mask,
    v2f*         __restrict__ partials)   // [BLOCKS_K1] (nll_sum, valid_cnt)
{
    __shared__ float wsum[WAVES_PER_BLOCK];
    __shared__ float wcnt[WAVES_PER_BLOCK];
    const int wave = threadIdx.x >> 6;
    const int lane = threadIdx.x & 63;
    const int r    = blockIdx.x * WAVES_PER_BLOCK + wave;  // 0 .. TOTAL_ROWS-1
    const int dir  = r >> 16;                 // 0 = successor, 1 = predecessor
    const int rr   = r & (ROWS_PER_DIR - 1);  // b*N + n
    const int n    = rr & (N_ - 1);

    const float* __restrict__ logits = dir ? pred_logits : succ_logits;
    const int*   __restrict__ labels = dir ? pred_labels : succ_labels;
    const float* __restrict__ row    = logits + (size_t)rr * N_;

    // wave-uniform metadata first (single cacheline, broadcast)
    const int label = labels[rr];
    const int valid = line_mask[rr];

    // 16 elements per lane: 4 coalesced nontemporal float4 loads
    const v4f* row4 = (const v4f*)row;
    v4f v0 = __builtin_nontemporal_load(row4 + 0 * 64 + lane);
    v4f v1 = __builtin_nontemporal_load(row4 + 1 * 64 + lane);
    v4f v2 = __builtin_nontemporal_load(row4 + 2 * 64 + lane);
    v4f v3 = __builtin_nontemporal_load(row4 + 3 * 64 + lane);

    // target index: diagonal if self-pointing, else clamped label
    const int t      = (label == -1) ? n : (label < 0 ? 0 : (label > N_ - 1 ? N_ - 1 : label));
    const int t_lane = (t >> 2) & 63;
    const int t_k    = t >> 8;
    const int t_c    = t & 3;
    v4f tv = (t_k == 0) ? v0 : (t_k == 1) ? v1 : (t_k == 2) ? v2 : v3;
    const float x_t = __shfl(tv[t_c], t_lane);   // row[t], wave-uniform after shfl

    // phase 1: row max
    float m;
    {
        v4f a = v0, b = v1;
        a.x = fmaxf(a.x, b.x); a.y = fmaxf(a.y, b.y); a.z = fmaxf(a.z, b.z); a.w = fmaxf(a.w, b.w);
        v4f c = v2; b = v3;
        c.x = fmaxf(c.x, b.x); c.y = fmaxf(c.y, b.y); c.z = fmaxf(c.z, b.z); c.w = fmaxf(c.w, b.w);
        a.x = fmaxf(a.x, c.x); a.y = fmaxf(a.y, c.y); a.z = fmaxf(a.z, c.z); a.w = fmaxf(a.w, c.w);
        m = fmaxf(fmaxf(a.x, a.y), fmaxf(a.z, a.w));
    }
    #pragma unroll
    for (int off = 32; off > 0; off >>= 1)
        m = fmaxf(m, __shfl_xor(m, off));

    // phase 2: sum of exp(x - m) at the global row max
    float s = 0.0f;
    s += __expf(v0.x - m); s += __expf(v0.y - m); s += __expf(v0.z - m); s += __expf(v0.w - m);
    s += __expf(v1.x - m); s += __expf(v1.y - m); s += __expf(v1.z - m); s += __expf(v1.w - m);
    s += __expf(v2.x - m); s += __expf(v2.y - m); s += __expf(v2.z - m); s += __expf(v2.w - m);
    s += __expf(v3.x - m); s += __expf(v3.y - m); s += __expf(v3.z - m); s += __expf(v3.w - m);
    #pragma unroll
    for (int off = 32; off > 0; off >>= 1)
        s += __shfl_xor(s, off);

    if (lane == 0) {
        float nll = 0.0f;
        if (valid) {
            if (label == -1) {
                // diag overwritten with row_max+1, target = diag:
                // nll = log( e^{-1} * (s - e^{d-m}) + 1 ),  d = row[n] = x_t
                nll = __logf((s - __expf(x_t - m)) * 0.36787944117144233f + 1.0f);
            } else {
                nll = m + __logf(s) - x_t;
            }
        }
        wsum[wave] = nll;
        // count valid lines only on the successor pass (dir is block-uniform)
        wcnt[wave] = (dir == 0 && valid) ? 1.0f : 0.0f;
    }
    __syncthreads();
    if (threadIdx.x == 0) {
        float acc = 0.0f, cnt = 0.0f;
        #pragma unroll
        for (int w = 0; w < WAVES_PER_BLOCK; ++w) { acc += wsum[w]; cnt += wcnt[w]; }
        v2f p; p.x = acc; p.y = cnt;
        partials[blockIdx.x] = p;   // temporal store: finalize reads from L2
    }
}

// Kernel 2: single-block deterministic finalize. Reads only the 128 KiB of
// freshly-written partials (L2-resident); line_mask is never touched here.
__global__ __launch_bounds__(1024) void finalize_kernel(
    const v2f*   __restrict__ partials,     // [BLOCKS_K1]
    const float* __restrict__ pred_weight,
    float*       __restrict__ out)
{
    const int tid = threadIdx.x;
    float ssum = 0.0f, psum = 0.0f, msum = 0.0f;
    for (int i = tid; i < BLOCKS_PER_DIR; i += 1024) {
        v2f sp = partials[i];
        v2f pp = partials[i + BLOCKS_PER_DIR];
        ssum += sp.x;
        msum += sp.y;
        psum += pp.x;
    }

    #pragma unroll
    for (int off = 32; off > 0; off >>= 1) {
        ssum += __shfl_xor(ssum, off);
        psum += __shfl_xor(psum, off);
        msum += __shfl_xor(msum, off);
    }

    __shared__ float sh[3][16];
    const int wave = tid >> 6, lane = tid & 63;
    if (lane == 0) { sh[0][wave] = ssum; sh[1][wave] = psum; sh[2][wave] = msum; }
    __syncthreads();
    if (tid == 0) {
        float S = 0.0f, P = 0.0f, M = 0.0f;
        #pragma unroll
        for (int w = 0; w < 16; ++w) { S += sh[0][w]; P += sh[1][w]; M += sh[2][w]; }
        const float denom = fmaxf(M, 1.0f);
        const float sl = S / denom, pl = P / denom;
        const float w  = pred_weight[0];
        out[0] = sl + w * pl;   // total_loss
        out[1] = sl;            // succ_loss
        out[2] = pl;            // pred_loss
        out[3] = M;             // num_valid
    }
}

extern "C" void kernel_launch(void* const* d_in, const int* in_sizes, int n_in,
                              void* d_out, int out_size, void* d_ws, size_t ws_size,
                              hipStream_t stream) {
    const float* succ_logits = (const float*)d_in[0];
    const int*   succ_labels = (const int*)  d_in[1];
    const float* pred_logits = (const float*)d_in[2];
    const int*   pred_labels = (const int*)  d_in[3];
    const int*   line_mask   = (const int*)  d_in[4];
    const float* pred_weight = (const float*)d_in[5];
    float* out      = (float*)d_out;
    v2f*   partials = (v2f*)d_ws;   // 16384 float2 = 128 KiB

    row_loss_kernel<<<BLOCKS_K1, 512, 0, stream>>>(
        succ_logits, succ_labels, pred_logits, pred_labels, line_mask, partials);
    finalize_kernel<<<1, 1024, 0, stream>>>(partials, pred_weight, out);
}